// Round 3
// baseline (358.270 us; speedup 1.0000x reference)
//
#include <hip/hip_runtime.h>
#include <math.h>

#define NWAVE   8
#define NORBIT  64
#define NATOMS  16384
#define NPAIRS  524288
#define HID     64
#define OC_LOOP 3
#define NSPEC   117
#define TBLN    (NSPEC * NSPEC)
#define NPADC   (NPAIRS + NATOMS * 8)   // 638976: max padded slot count

// ---------- helpers ----------
__device__ __forceinline__ float wred_sum(float v) {
#pragma unroll
    for (int o = 1; o < 64; o <<= 1) v += __shfl_xor(v, o, 64);
    return v;
}

__device__ __forceinline__ float ln_silu(float h, float gg, float bb) {
    float m = wred_sum(h) * (1.f / 64.f);
    float c = h - m;
    float v = wred_sum(c * c) * (1.f / 64.f);
    float y = c * rsqrtf(v + 1e-5f) * gg + bb;
    return y / (1.f + expf(-y));
}

__device__ __forceinline__ float dot4(float4 a, float4 b) {
    return a.x * b.x + a.y * b.y + a.z * b.z + a.w * b.w;
}

// ---------- CSR build (padded to multiple of 8 per atom) ----------
__global__ void k_hist(const int* __restrict__ ai0, int* __restrict__ cnt) {
    int p = blockIdx.x * 256 + threadIdx.x;
    if (p < NPAIRS) atomicAdd(&cnt[ai0[p]], 1);
}

__global__ void k_scan(const int* __restrict__ cnt, int* __restrict__ offs,
                       int* __restrict__ cursor) {
    __shared__ int sums[1024];
    int t = threadIdx.x;
    int base = t * 16;
    int v[16];
    int s = 0;
#pragma unroll
    for (int u = 0; u < 16; u++) { v[u] = (cnt[base + u] + 7) & ~7; s += v[u]; }
    sums[t] = s;
    __syncthreads();
    for (int d = 1; d < 1024; d <<= 1) {
        int x = (t >= d) ? sums[t - d] : 0;
        __syncthreads();
        sums[t] += x;
        __syncthreads();
    }
    int run = (t == 0) ? 0 : sums[t - 1];
#pragma unroll
    for (int u = 0; u < 16; u++) {
        offs[base + u] = run;
        cursor[base + u] = run;
        run += v[u];
    }
    if (t == 1023) offs[NATOMS] = run;
}

__global__ void k_scatter(const int* __restrict__ ai0, int* __restrict__ cursor,
                          int* __restrict__ plist) {
    int p = blockIdx.x * 256 + threadIdx.x;
    if (p < NPAIRS) {
        int pos = atomicAdd(&cursor[ai0[p]], 1);
        plist[pos] = p;
    }
}

// ---------- weight transposes ----------
__global__ void k_prep(const float* __restrict__ embc_W2, const float* __restrict__ oc_W1,
                       const float* __restrict__ oc_W2, const float* __restrict__ out_W1,
                       const float* __restrict__ ccoeff,
                       float* __restrict__ embc_W2t, float* __restrict__ oc_W1t,
                       float* __restrict__ oc_W2t, float* __restrict__ out_W1t,
                       float* __restrict__ cct) {
    int idx = blockIdx.x * 256 + threadIdx.x;
    if (idx < 4096) {
        int o = idx >> 6, i = idx & 63;
        embc_W2t[o * 64 + i] = embc_W2[i * 64 + o];
    }
    int t = idx - 4096;
    if (t >= 0 && t < 12288) {
        int l = t >> 12, r = t & 4095, o = r >> 6, i = r & 63;
        oc_W1t[l * 4096 + o * 64 + i] = oc_W1[l * 4096 + i * 64 + o];
    }
    t = idx - 16384;
    if (t >= 0 && t < 1536) {
        int l = t >> 9, r = t & 511, o = r >> 6, i = r & 63;
        oc_W2t[l * 512 + o * 64 + i] = oc_W2[l * 512 + i * 8 + o];
    }
    t = idx - 17920;
    if (t >= 0 && t < 4096) {
        int o = t >> 6, i = t & 63;
        out_W1t[o * 64 + i] = out_W1[i * 64 + o];
    }
    t = idx - 22016;
    if (t >= 0 && t < 4096) {
        int lr = t >> 9, km = t & 511, k = km >> 6, m = km & 63;
        cct[(lr * 64 + m) * 8 + k] = ccoeff[(lr * 8 + k) * 64 + m];
    }
}

// ---------- embc MLP per atom ----------
__global__ void k_center(const int* __restrict__ spec,
                         const float* __restrict__ W1, const float* __restrict__ b1,
                         const float* __restrict__ g,  const float* __restrict__ be,
                         const float* __restrict__ W2t, const float* __restrict__ b2,
                         float* __restrict__ ccoef) {
    __shared__ float h_s[4][64];
    int lane = threadIdx.x & 63, slot = threadIdx.x >> 6;
    int atom = blockIdx.x * 4 + slot;
    int s = spec[atom] + 1;
    float h = W1[s * 64 + lane] + b1[lane];
    h = ln_silu(h, g[lane], be[lane]);
    h_s[slot][lane] = h;
    __syncthreads();
    float o = b2[lane];
    const float4* wp = (const float4*)(W2t + lane * 64);
    const float4* hp = (const float4*)h_s[slot];
#pragma unroll
    for (int t = 0; t < 16; t++) o += dot4(wp[t], hp[t]);
    ccoef[atom * 64 + lane] = o;
}

// ---------- embn MLP per unique species pair ----------
__global__ void k_table(const float* __restrict__ W1, const float* __restrict__ b1,
                        const float* __restrict__ g,  const float* __restrict__ be,
                        const float* __restrict__ W2, const float* __restrict__ b2,
                        float* __restrict__ table) {
    __shared__ float h_s[4][64];
    int lane = threadIdx.x & 63, slot = threadIdx.x >> 6;
    int key = blockIdx.x * 4 + slot;
    int kk = (key < TBLN) ? key : 0;
    int s0 = kk / NSPEC + 1, s1 = kk % NSPEC + 1;
    float h = W1[s0 * 64 + lane] + W1[s1 * 64 + lane] + b1[lane];
    h = ln_silu(h, g[lane], be[lane]);
    h_s[slot][lane] = h;
    __syncthreads();
    if (lane < 24 && key < TBLN) {
        float o = b2[lane];
#pragma unroll 8
        for (int i = 0; i < 64; i++) o += h_s[slot][i] * W2[i * 24 + lane];
        table[key * 24 + lane] = o;
    }
}

// ---------- per-pair: transposed streams ----------
__global__ void k_pair2(const float* __restrict__ cart, const int* __restrict__ aidx,
                        const int* __restrict__ spec,  const float* __restrict__ table,
                        const int* __restrict__ plist, const int* __restrict__ total_p,
                        float* __restrict__ dist_out, float* __restrict__ ang_t,
                        float* __restrict__ rad_t,    float* __restrict__ prod_t,
                        int* __restrict__ neigh) {
    int pos = blockIdx.x * 256 + threadIdx.x;
    if (pos >= total_p[0]) return;
    int p = plist[pos];
    if (p < 0) {  // pad slot inside a segment: zero contribution
#pragma unroll
        for (int j = 0; j < 4; j++) ang_t[(size_t)j * NPADC + pos] = 0.f;
#pragma unroll
        for (int k = 0; k < 8; k++) {
            rad_t[(size_t)k * NPADC + pos] = 0.f;
            prod_t[(size_t)k * NPADC + pos] = 0.f;
        }
        neigh[pos] = 0;
        return;
    }
    int i0 = aidx[p];
    int i1 = aidx[NPAIRS + p];
    float dv0 = cart[i0 * 3 + 0] - cart[i1 * 3 + 0];
    float dv1 = cart[i0 * 3 + 1] - cart[i1 * 3 + 1];
    float dv2 = cart[i0 * 3 + 2] - cart[i1 * 3 + 2];
    float d = sqrtf(dv0 * dv0 + dv1 * dv1 + dv2 * dv2);
    dist_out[(size_t)p * 3 + 0] = dv0;
    dist_out[(size_t)p * 3 + 1] = dv1;
    dist_out[(size_t)p * 3 + 2] = dv2;

    int key = spec[i0] * NSPEC + spec[i1];
    const float4* ne = (const float4*)(table + (size_t)key * 24);
    float4 it_a = ne[0], it_b = ne[1];
    float4 al_a = ne[2], al_b = ne[3];
    float4 mu_a = ne[4], mu_b = ne[5];

    float cth = cosf(d * (float)(M_PI / 4.0));
    float t0 = 0.5f * cth + 0.5f;
    float fc = t0 * t0;

    ang_t[(size_t)0 * NPADC + pos] = fc;
    ang_t[(size_t)1 * NPADC + pos] = dv0 * fc;
    ang_t[(size_t)2 * NPADC + pos] = dv1 * fc;
    ang_t[(size_t)3 * NPADC + pos] = dv2 * fc;

    float r[8], it[8];
    float t;
    t = al_a.x * (d - mu_a.x); r[0] = expf(-t * t); it[0] = it_a.x;
    t = al_a.y * (d - mu_a.y); r[1] = expf(-t * t); it[1] = it_a.y;
    t = al_a.z * (d - mu_a.z); r[2] = expf(-t * t); it[2] = it_a.z;
    t = al_a.w * (d - mu_a.w); r[3] = expf(-t * t); it[3] = it_a.w;
    t = al_b.x * (d - mu_b.x); r[4] = expf(-t * t); it[4] = it_b.x;
    t = al_b.y * (d - mu_b.y); r[5] = expf(-t * t); it[5] = it_b.y;
    t = al_b.z * (d - mu_b.z); r[6] = expf(-t * t); it[6] = it_b.z;
    t = al_b.w * (d - mu_b.w); r[7] = expf(-t * t); it[7] = it_b.w;
#pragma unroll
    for (int k = 0; k < 8; k++) {
        rad_t[(size_t)k * NPADC + pos] = r[k];
        prod_t[(size_t)k * NPADC + pos] = r[k] * it[k];
    }
    neigh[pos] = i1;
}

// ---------- shared epilogue: contraction + oc-MLP ----------
// co_s: reduced co[4][8] in LDS; returns nothing (writes S_out)
template <bool ACC>
__device__ __forceinline__ void dens_mlp_oc(
        int atom, int lane, int slot, const float* co_row,
        const float* __restrict__ ccoef, const float* __restrict__ cct_l,
        const float* __restrict__ S_in,
        const float* __restrict__ W1t, const float* __restrict__ b1,
        const float* __restrict__ g,  const float* __restrict__ be,
        const float* __restrict__ W2t, const float* __restrict__ b2,
        float* __restrict__ S_out,
        float (*dens_s)[64], float (*h_s)[64]) {
    // unpack co (broadcast reads)
    float co[32];
    const float4* cp = (const float4*)co_row;
#pragma unroll
    for (int q = 0; q < 8; q++) {
        float4 v = cp[q];
        co[q * 4 + 0] = v.x; co[q * 4 + 1] = v.y; co[q * 4 + 2] = v.z; co[q * 4 + 3] = v.w;
    }
    const float4* c0 = (const float4*)(cct_l + lane * 8);          // row 0, k=0..7
    const float4* c1 = (const float4*)(cct_l + 512 + lane * 8);    // row 1
    float4 ca0 = c0[0], ca1 = c0[1];
    float4 cb0 = c1[0], cb1 = c1[1];
    float dens = ccoef[atom * 64 + lane];
    {
        float s = co[0] * ca0.x + co[1] * ca0.y + co[2] * ca0.z + co[3] * ca0.w
                + co[4] * ca1.x + co[5] * ca1.y + co[6] * ca1.z + co[7] * ca1.w;
        dens += s * s;
    }
#pragma unroll
    for (int j = 1; j < 4; j++) {
        const float* cj = co + j * 8;
        float s = cj[0] * cb0.x + cj[1] * cb0.y + cj[2] * cb0.z + cj[3] * cb0.w
                + cj[4] * cb1.x + cj[5] * cb1.y + cj[6] * cb1.z + cj[7] * cb1.w;
        dens += s * s;
    }
    dens_s[slot][lane] = dens;
    __syncthreads();

    float h = b1[lane];
    const float4* wp = (const float4*)(W1t + lane * 64);
    const float4* dp = (const float4*)dens_s[slot];
#pragma unroll
    for (int q = 0; q < 16; q++) h += dot4(wp[q], dp[q]);
    h = ln_silu(h, g[lane], be[lane]);
    h_s[slot][lane] = h;
    __syncthreads();

    int o = lane >> 3, seg = lane & 7;
    const float4* w2p = (const float4*)(W2t + o * 64 + seg * 8);
    const float4* hp  = (const float4*)(&h_s[slot][seg * 8]);
    float part = dot4(w2p[0], hp[0]) + dot4(w2p[1], hp[1]);
    part += __shfl_xor(part, 1, 64);
    part += __shfl_xor(part, 2, 64);
    part += __shfl_xor(part, 4, 64);
    if (seg == 0) {
        float val = part + b2[o];
        if (ACC) val += S_in[(size_t)atom * 8 + o];
        S_out[(size_t)atom * 8 + o] = val;
    }
}

// ---------- pass 0: co0 from prod stream; write co0; oc_0 -> S_out ----------
__global__ void k_dens0(const int* __restrict__ offs,
                        const float* __restrict__ ang_t, const float* __restrict__ prod_t,
                        float* __restrict__ co0,
                        const float* __restrict__ ccoef, const float* __restrict__ cct_l,
                        const float* __restrict__ W1t, const float* __restrict__ b1,
                        const float* __restrict__ g,  const float* __restrict__ be,
                        const float* __restrict__ W2t, const float* __restrict__ b2,
                        float* __restrict__ S_out) {
    __shared__ float co_s[4][32];
    __shared__ float dens_s[4][64];
    __shared__ float h_s[4][64];
    int lane = threadIdx.x & 63, slot = threadIdx.x >> 6;
    int atom = blockIdx.x * 4 + slot;
    int start = offs[atom], cnt = offs[atom + 1] - start;
    int half = lane >> 5, jk = lane & 31, j = jk >> 3, k = jk & 7;
    const float* aj = ang_t + (size_t)j * NPADC + start;
    const float* pk = prod_t + (size_t)k * NPADC + start;
    float acc = 0.f;
#pragma unroll 2
    for (int q = half * 4; q < cnt; q += 8) {
        float4 a = *(const float4*)(aj + q);
        float4 pr = *(const float4*)(pk + q);
        acc += dot4(a, pr);
    }
    acc += __shfl_xor(acc, 32, 64);
    if (lane < 32) {
        co0[(size_t)atom * 32 + jk] = acc;
        co_s[slot][jk] = acc;
    }
    __syncthreads();
    dens_mlp_oc<false>(atom, lane, slot, co_s[slot], ccoef, cct_l, nullptr,
                       W1t, b1, g, be, W2t, b2, S_out, dens_s, h_s);
}

// ---------- passes 1..2: gather S; oc_l -> S_out = o + S_in[atom] ----------
__global__ void k_densl(const int* __restrict__ offs,
                        const float* __restrict__ ang_t, const float* __restrict__ rad_t,
                        const int* __restrict__ neigh,  const float* __restrict__ co0,
                        const float* __restrict__ S_in,
                        const float* __restrict__ ccoef, const float* __restrict__ cct_l,
                        const float* __restrict__ W1t, const float* __restrict__ b1,
                        const float* __restrict__ g,  const float* __restrict__ be,
                        const float* __restrict__ W2t, const float* __restrict__ b2,
                        float* __restrict__ S_out) {
    __shared__ float co_s[4][32];
    __shared__ float dens_s[4][64];
    __shared__ float h_s[4][64];
    int lane = threadIdx.x & 63, slot = threadIdx.x >> 6;
    int atom = blockIdx.x * 4 + slot;
    int start = offs[atom], cnt = offs[atom + 1] - start;
    int half = lane >> 5, jk = lane & 31, j = jk >> 3, k = jk & 7;
    const float* aj = ang_t + (size_t)j * NPADC + start;
    const float* rk = rad_t + (size_t)k * NPADC + start;
    const int*   nb = neigh + start;
    float acc = 0.f;
#pragma unroll 2
    for (int q = half * 4; q < cnt; q += 8) {
        float4 a = *(const float4*)(aj + q);
        float4 r = *(const float4*)(rk + q);
        int4   n = *(const int4*)(nb + q);
        float s0 = S_in[(size_t)n.x * 8 + k];
        float s1 = S_in[(size_t)n.y * 8 + k];
        float s2 = S_in[(size_t)n.z * 8 + k];
        float s3 = S_in[(size_t)n.w * 8 + k];
        acc += a.x * r.x * s0 + a.y * r.y * s1 + a.z * r.z * s2 + a.w * r.w * s3;
    }
    acc += __shfl_xor(acc, 32, 64);
    if (lane < 32) co_s[slot][jk] = acc + co0[(size_t)atom * 32 + jk];
    __syncthreads();
    dens_mlp_oc<true>(atom, lane, slot, co_s[slot], ccoef, cct_l, S_in,
                      W1t, b1, g, be, W2t, b2, S_out, dens_s, h_s);
}

// ---------- final pass: gather S; out-MLP -> scalar ----------
__global__ void k_dens_out(const int* __restrict__ offs,
                           const float* __restrict__ ang_t, const float* __restrict__ rad_t,
                           const int* __restrict__ neigh,  const float* __restrict__ co0,
                           const float* __restrict__ S_in,
                           const float* __restrict__ ccoef, const float* __restrict__ cct_l,
                           const int* __restrict__ spec,
                           const float* __restrict__ W1t, const float* __restrict__ b1,
                           const float* __restrict__ g,  const float* __restrict__ be,
                           const float* __restrict__ W2, const float* __restrict__ b2,
                           float* __restrict__ out) {
    __shared__ float co_s[4][32];
    __shared__ float dens_s[4][64];
    int lane = threadIdx.x & 63, slot = threadIdx.x >> 6;
    int atom = blockIdx.x * 4 + slot;
    int start = offs[atom], cnt = offs[atom + 1] - start;
    int half = lane >> 5, jk = lane & 31, j = jk >> 3, k = jk & 7;
    const float* aj = ang_t + (size_t)j * NPADC + start;
    const float* rk = rad_t + (size_t)k * NPADC + start;
    const int*   nb = neigh + start;
    float acc = 0.f;
#pragma unroll 2
    for (int q = half * 4; q < cnt; q += 8) {
        float4 a = *(const float4*)(aj + q);
        float4 r = *(const float4*)(rk + q);
        int4   n = *(const int4*)(nb + q);
        float s0 = S_in[(size_t)n.x * 8 + k];
        float s1 = S_in[(size_t)n.y * 8 + k];
        float s2 = S_in[(size_t)n.z * 8 + k];
        float s3 = S_in[(size_t)n.w * 8 + k];
        acc += a.x * r.x * s0 + a.y * r.y * s1 + a.z * r.z * s2 + a.w * r.w * s3;
    }
    acc += __shfl_xor(acc, 32, 64);
    if (lane < 32) co_s[slot][jk] = acc + co0[(size_t)atom * 32 + jk];
    __syncthreads();

    float co[32];
    const float4* cp = (const float4*)co_s[slot];
#pragma unroll
    for (int q = 0; q < 8; q++) {
        float4 v = cp[q];
        co[q * 4 + 0] = v.x; co[q * 4 + 1] = v.y; co[q * 4 + 2] = v.z; co[q * 4 + 3] = v.w;
    }
    const float4* c0 = (const float4*)(cct_l + lane * 8);
    const float4* c1 = (const float4*)(cct_l + 512 + lane * 8);
    float4 ca0 = c0[0], ca1 = c0[1];
    float4 cb0 = c1[0], cb1 = c1[1];
    float dens = ccoef[atom * 64 + lane];
    {
        float s = co[0] * ca0.x + co[1] * ca0.y + co[2] * ca0.z + co[3] * ca0.w
                + co[4] * ca1.x + co[5] * ca1.y + co[6] * ca1.z + co[7] * ca1.w;
        dens += s * s;
    }
#pragma unroll
    for (int j2 = 1; j2 < 4; j2++) {
        const float* cj = co + j2 * 8;
        float s = cj[0] * cb0.x + cj[1] * cb0.y + cj[2] * cb0.z + cj[3] * cb0.w
                + cj[4] * cb1.x + cj[5] * cb1.y + cj[6] * cb1.z + cj[7] * cb1.w;
        dens += s * s;
    }
    dens_s[slot][lane] = dens;
    __syncthreads();

    float h = b1[lane];
    const float4* wp = (const float4*)(W1t + lane * 64);
    const float4* dp = (const float4*)dens_s[slot];
#pragma unroll
    for (int q = 0; q < 16; q++) h += dot4(wp[q], dp[q]);
    h = ln_silu(h, g[lane], be[lane]);
    float s = wred_sum(h * W2[lane]);
    if (lane == 0) {
        float mask = (spec[atom] >= 0) ? 1.f : 0.f;
        out[atom] = (s + b2[0]) * mask;
    }
}

extern "C" void kernel_launch(void* const* d_in, const int* in_sizes, int n_in,
                              void* d_out, int out_size, void* d_ws, size_t ws_size,
                              hipStream_t stream) {
    const float* cart   = (const float*)d_in[0];
    const int*   aidx   = (const int*)d_in[1];
    const int*   spec   = (const int*)d_in[2];
    const float* ccoeff = (const float*)d_in[4];
    const float* embn_W1 = (const float*)d_in[5];
    const float* embn_b1 = (const float*)d_in[6];
    const float* embn_g  = (const float*)d_in[7];
    const float* embn_be = (const float*)d_in[8];
    const float* embn_W2 = (const float*)d_in[9];
    const float* embn_b2 = (const float*)d_in[10];
    const float* embc_W1 = (const float*)d_in[11];
    const float* embc_b1 = (const float*)d_in[12];
    const float* embc_g  = (const float*)d_in[13];
    const float* embc_be = (const float*)d_in[14];
    const float* embc_W2 = (const float*)d_in[15];
    const float* embc_b2 = (const float*)d_in[16];
    const float* oc_W1 = (const float*)d_in[17];
    const float* oc_b1 = (const float*)d_in[18];
    const float* oc_g  = (const float*)d_in[19];
    const float* oc_be = (const float*)d_in[20];
    const float* oc_W2 = (const float*)d_in[21];
    const float* oc_b2 = (const float*)d_in[22];
    const float* out_W1 = (const float*)d_in[23];
    const float* out_b1 = (const float*)d_in[24];
    const float* out_g  = (const float*)d_in[25];
    const float* out_be = (const float*)d_in[26];
    const float* out_W2 = (const float*)d_in[27];
    const float* out_b2 = (const float*)d_in[28];

    float* outp = (float*)d_out;

    char* ws = (char*)d_ws;
    size_t off = 0;
    auto carve = [&](size_t bytes) { size_t o = off; off = (off + bytes + 255) & ~(size_t)255; return o; };
    float* ang_t   = (float*)(ws + carve((size_t)4 * NPADC * 4));
    float* rad_t   = (float*)(ws + carve((size_t)8 * NPADC * 4));
    float* prod_t  = (float*)(ws + carve((size_t)8 * NPADC * 4));
    int*   neigh   = (int*)(ws + carve((size_t)NPADC * 4));
    int*   plist   = (int*)(ws + carve((size_t)NPADC * 4));
    float* ccenter = (float*)(ws + carve((size_t)NATOMS * 64 * 4));
    float* co0     = (float*)(ws + carve((size_t)NATOMS * 32 * 4));
    float* Sa      = (float*)(ws + carve((size_t)NATOMS * 8 * 4));
    float* Sb      = (float*)(ws + carve((size_t)NATOMS * 8 * 4));
    float* table   = (float*)(ws + carve((size_t)TBLN * 24 * 4));
    float* embc_W2t= (float*)(ws + carve(4096 * 4));
    float* oc_W1t  = (float*)(ws + carve(12288 * 4));
    float* oc_W2t  = (float*)(ws + carve(1536 * 4));
    float* out_W1t = (float*)(ws + carve(4096 * 4));
    float* cct     = (float*)(ws + carve(4096 * 4));
    int*   cnt     = (int*)(ws + carve((size_t)NATOMS * 4));
    int*   offs    = (int*)(ws + carve((size_t)(NATOMS + 1) * 4));
    int*   cursor  = (int*)(ws + carve((size_t)NATOMS * 4));

    hipMemsetAsync(cnt, 0, (size_t)NATOMS * 4, stream);
    hipMemsetAsync(plist, 0xFF, (size_t)NPADC * 4, stream);

    k_hist<<<NPAIRS / 256, 256, 0, stream>>>(aidx, cnt);
    k_scan<<<1, 1024, 0, stream>>>(cnt, offs, cursor);
    k_scatter<<<NPAIRS / 256, 256, 0, stream>>>(aidx, cursor, plist);

    k_prep<<<(26112 + 255) / 256, 256, 0, stream>>>(embc_W2, oc_W1, oc_W2, out_W1, ccoeff,
                                                    embc_W2t, oc_W1t, oc_W2t, out_W1t, cct);
    k_center<<<NATOMS / 4, 256, 0, stream>>>(spec, embc_W1, embc_b1, embc_g, embc_be,
                                             embc_W2t, embc_b2, ccenter);
    k_table<<<(TBLN + 3) / 4, 256, 0, stream>>>(embn_W1, embn_b1, embn_g, embn_be,
                                                embn_W2, embn_b2, table);

    k_pair2<<<NPADC / 256, 256, 0, stream>>>(cart, aidx, spec, table, plist, offs + NATOMS,
                                             outp, ang_t, rad_t, prod_t, neigh);

    // l=0
    k_dens0<<<NATOMS / 4, 256, 0, stream>>>(offs, ang_t, prod_t, co0, ccenter, cct + 0 * 1024,
                                            oc_W1t + 0 * 4096, oc_b1 + 0 * 64, oc_g + 0 * 64,
                                            oc_be + 0 * 64, oc_W2t + 0 * 512, oc_b2 + 0 * 8, Sa);
    // l=1
    k_densl<<<NATOMS / 4, 256, 0, stream>>>(offs, ang_t, rad_t, neigh, co0, Sa, ccenter,
                                            cct + 1 * 1024, oc_W1t + 1 * 4096, oc_b1 + 1 * 64,
                                            oc_g + 1 * 64, oc_be + 1 * 64, oc_W2t + 1 * 512,
                                            oc_b2 + 1 * 8, Sb);
    // l=2
    k_densl<<<NATOMS / 4, 256, 0, stream>>>(offs, ang_t, rad_t, neigh, co0, Sb, ccenter,
                                            cct + 2 * 1024, oc_W1t + 2 * 4096, oc_b1 + 2 * 64,
                                            oc_g + 2 * 64, oc_be + 2 * 64, oc_W2t + 2 * 512,
                                            oc_b2 + 2 * 8, Sa);
    // final
    k_dens_out<<<NATOMS / 4, 256, 0, stream>>>(offs, ang_t, rad_t, neigh, co0, Sa, ccenter,
                                               cct + 3 * 1024, spec, out_W1t, out_b1, out_g,
                                               out_be, out_W2, out_b2, outp + (size_t)NPAIRS * 3);
}

// Round 4
// 302.291 us; speedup vs baseline: 1.1852x; 1.1852x over previous
//
#include <hip/hip_runtime.h>
#include <math.h>

#define NWAVE   8
#define NORBIT  64
#define NATOMS  16384
#define NPAIRS  524288
#define HID     64
#define OC_LOOP 3
#define NSPEC   117
#define TBLN    (NSPEC * NSPEC)
#define NPADC   (NPAIRS + NATOMS * 8)   // 655360: max padded slot count

// ---------- helpers ----------
__device__ __forceinline__ float wred_sum(float v) {
#pragma unroll
    for (int o = 1; o < 64; o <<= 1) v += __shfl_xor(v, o, 64);
    return v;
}

__device__ __forceinline__ float ln_silu(float h, float gg, float bb) {
    float m = wred_sum(h) * (1.f / 64.f);
    float c = h - m;
    float v = wred_sum(c * c) * (1.f / 64.f);
    float y = c * rsqrtf(v + 1e-5f) * gg + bb;
    return y / (1.f + expf(-y));
}

__device__ __forceinline__ float dot4(float4 a, float4 b) {
    return a.x * b.x + a.y * b.y + a.z * b.z + a.w * b.w;
}

// ---------- CSR build (padded to multiple of 8 per atom) ----------
__global__ void k_hist(const int* __restrict__ ai0, int* __restrict__ cnt) {
    int p = blockIdx.x * 256 + threadIdx.x;
    if (p < NPAIRS) atomicAdd(&cnt[ai0[p]], 1);
}

__global__ void k_scan(const int* __restrict__ cnt, int* __restrict__ offs,
                       int* __restrict__ cursor) {
    __shared__ int sums[1024];
    int t = threadIdx.x;
    int base = t * 16;
    int v[16];
    int s = 0;
#pragma unroll
    for (int u = 0; u < 16; u++) { v[u] = (cnt[base + u] + 7) & ~7; s += v[u]; }
    sums[t] = s;
    __syncthreads();
    for (int d = 1; d < 1024; d <<= 1) {
        int x = (t >= d) ? sums[t - d] : 0;
        __syncthreads();
        sums[t] += x;
        __syncthreads();
    }
    int run = (t == 0) ? 0 : sums[t - 1];
#pragma unroll
    for (int u = 0; u < 16; u++) {
        offs[base + u] = run;
        cursor[base + u] = run;
        run += v[u];
    }
    if (t == 1023) offs[NATOMS] = run;
}

__global__ void k_scatter(const int* __restrict__ ai0, int* __restrict__ cursor,
                          int* __restrict__ plist) {
    int p = blockIdx.x * 256 + threadIdx.x;
    if (p < NPAIRS) {
        int pos = atomicAdd(&cursor[ai0[p]], 1);
        plist[pos] = p;
    }
}

// ---------- weight transposes: embc_W2t, oc_W2t, out nothing, cct ----------
__global__ void k_prep(const float* __restrict__ embc_W2, const float* __restrict__ oc_W2,
                       const float* __restrict__ ccoeff,
                       float* __restrict__ embc_W2t, float* __restrict__ oc_W2t,
                       float* __restrict__ cct) {
    int idx = blockIdx.x * 256 + threadIdx.x;
    if (idx < 4096) {
        int o = idx >> 6, i = idx & 63;
        embc_W2t[o * 64 + i] = embc_W2[i * 64 + o];
    }
    int t = idx - 4096;
    if (t >= 0 && t < 1536) {
        int l = t >> 9, r = t & 511, o = r >> 6, i = r & 63;
        oc_W2t[l * 512 + o * 64 + i] = oc_W2[l * 512 + i * 8 + o];
    }
    t = idx - 5632;
    if (t >= 0 && t < 4096) {
        int lr = t >> 9, km = t & 511, k = km >> 6, m = km & 63;
        cct[(lr * 64 + m) * 8 + k] = ccoeff[(lr * 8 + k) * 64 + m];
    }
}

// ---------- embc MLP per atom ----------
__global__ void k_center(const int* __restrict__ spec,
                         const float* __restrict__ W1, const float* __restrict__ b1,
                         const float* __restrict__ g,  const float* __restrict__ be,
                         const float* __restrict__ W2t, const float* __restrict__ b2,
                         float* __restrict__ ccoef) {
    __shared__ float h_s[4][64];
    int lane = threadIdx.x & 63, slot = threadIdx.x >> 6;
    int atom = blockIdx.x * 4 + slot;
    int s = spec[atom] + 1;
    float h = W1[s * 64 + lane] + b1[lane];
    h = ln_silu(h, g[lane], be[lane]);
    h_s[slot][lane] = h;
    __syncthreads();
    float o = b2[lane];
    const float4* wp = (const float4*)(W2t + lane * 64);
    const float4* hp = (const float4*)h_s[slot];
#pragma unroll
    for (int t = 0; t < 16; t++) o += dot4(wp[t], hp[t]);
    ccoef[atom * 64 + lane] = o;
}

// ---------- embn MLP per unique species pair ----------
__global__ void k_table(const float* __restrict__ W1, const float* __restrict__ b1,
                        const float* __restrict__ g,  const float* __restrict__ be,
                        const float* __restrict__ W2, const float* __restrict__ b2,
                        float* __restrict__ table) {
    __shared__ float h_s[4][64];
    int lane = threadIdx.x & 63, slot = threadIdx.x >> 6;
    int key = blockIdx.x * 4 + slot;
    int kk = (key < TBLN) ? key : 0;
    int s0 = kk / NSPEC + 1, s1 = kk % NSPEC + 1;
    float h = W1[s0 * 64 + lane] + W1[s1 * 64 + lane] + b1[lane];
    h = ln_silu(h, g[lane], be[lane]);
    h_s[slot][lane] = h;
    __syncthreads();
    if (lane < 24 && key < TBLN) {
        float o = b2[lane];
#pragma unroll 8
        for (int i = 0; i < 64; i++) o += h_s[slot][i] * W2[i * 24 + lane];
        table[key * 24 + lane] = o;
    }
}

// ---------- per-pair: transposed streams ----------
__global__ void k_pair2(const float* __restrict__ cart, const int* __restrict__ aidx,
                        const int* __restrict__ spec,  const float* __restrict__ table,
                        const int* __restrict__ plist, const int* __restrict__ total_p,
                        float* __restrict__ dist_out, float* __restrict__ ang_t,
                        float* __restrict__ rad_t,    float* __restrict__ prod_t,
                        int* __restrict__ neigh) {
    int pos = blockIdx.x * 256 + threadIdx.x;
    if (pos >= total_p[0]) return;
    int p = plist[pos];
    if (p < 0) {
#pragma unroll
        for (int j = 0; j < 4; j++) ang_t[(size_t)j * NPADC + pos] = 0.f;
#pragma unroll
        for (int k = 0; k < 8; k++) {
            rad_t[(size_t)k * NPADC + pos] = 0.f;
            prod_t[(size_t)k * NPADC + pos] = 0.f;
        }
        neigh[pos] = 0;
        return;
    }
    int i0 = aidx[p];
    int i1 = aidx[NPAIRS + p];
    float dv0 = cart[i0 * 3 + 0] - cart[i1 * 3 + 0];
    float dv1 = cart[i0 * 3 + 1] - cart[i1 * 3 + 1];
    float dv2 = cart[i0 * 3 + 2] - cart[i1 * 3 + 2];
    float d = sqrtf(dv0 * dv0 + dv1 * dv1 + dv2 * dv2);
    dist_out[(size_t)p * 3 + 0] = dv0;
    dist_out[(size_t)p * 3 + 1] = dv1;
    dist_out[(size_t)p * 3 + 2] = dv2;

    int key = spec[i0] * NSPEC + spec[i1];
    const float4* ne = (const float4*)(table + (size_t)key * 24);
    float4 it_a = ne[0], it_b = ne[1];
    float4 al_a = ne[2], al_b = ne[3];
    float4 mu_a = ne[4], mu_b = ne[5];

    float cth = cosf(d * (float)(M_PI / 4.0));
    float t0 = 0.5f * cth + 0.5f;
    float fc = t0 * t0;

    ang_t[(size_t)0 * NPADC + pos] = fc;
    ang_t[(size_t)1 * NPADC + pos] = dv0 * fc;
    ang_t[(size_t)2 * NPADC + pos] = dv1 * fc;
    ang_t[(size_t)3 * NPADC + pos] = dv2 * fc;

    float r[8], it[8];
    float t;
    t = al_a.x * (d - mu_a.x); r[0] = expf(-t * t); it[0] = it_a.x;
    t = al_a.y * (d - mu_a.y); r[1] = expf(-t * t); it[1] = it_a.y;
    t = al_a.z * (d - mu_a.z); r[2] = expf(-t * t); it[2] = it_a.z;
    t = al_a.w * (d - mu_a.w); r[3] = expf(-t * t); it[3] = it_a.w;
    t = al_b.x * (d - mu_b.x); r[4] = expf(-t * t); it[4] = it_b.x;
    t = al_b.y * (d - mu_b.y); r[5] = expf(-t * t); it[5] = it_b.y;
    t = al_b.z * (d - mu_b.z); r[6] = expf(-t * t); it[6] = it_b.z;
    t = al_b.w * (d - mu_b.w); r[7] = expf(-t * t); it[7] = it_b.w;
#pragma unroll
    for (int k = 0; k < 8; k++) {
        rad_t[(size_t)k * NPADC + pos] = r[k];
        prod_t[(size_t)k * NPADC + pos] = r[k] * it[k];
    }
    neigh[pos] = i1;
}

// ---------- gather pass: co[atom][32]. half-wave (32 lanes) per atom, no LDS ----------
template <bool HAS_S>
__global__ __launch_bounds__(256, 8)
void k_co(const int* __restrict__ offs,
          const float* __restrict__ ang_t, const float* __restrict__ rstream,
          const int* __restrict__ neigh,  const float* __restrict__ co0,
          const float* __restrict__ S_in, float* __restrict__ co_out) {
    int lane = threadIdx.x & 63;
    int wid  = (blockIdx.x * 256 + threadIdx.x) >> 6;
    int half = lane >> 5, jk = lane & 31, j = jk >> 3, k = jk & 7;
    int atom = wid * 2 + half;
    int start = offs[atom], cnt = offs[atom + 1] - start;
    const float* aj = ang_t + (size_t)j * NPADC + start;
    const float* rk = rstream + (size_t)k * NPADC + start;
    const int*   nb = neigh + start;
    float acc = 0.f;
#pragma unroll 2
    for (int q = 0; q < cnt; q += 4) {
        float4 a = *(const float4*)(aj + q);
        float4 r = *(const float4*)(rk + q);
        if (HAS_S) {
            int4 n = *(const int4*)(nb + q);
            acc += a.x * r.x * S_in[(size_t)n.x * 8 + k]
                 + a.y * r.y * S_in[(size_t)n.y * 8 + k]
                 + a.z * r.z * S_in[(size_t)n.z * 8 + k]
                 + a.w * r.w * S_in[(size_t)n.w * 8 + k];
        } else {
            acc += dot4(a, r);
        }
    }
    if (HAS_S) acc += co0[(size_t)atom * 32 + jk];
    co_out[(size_t)atom * 32 + jk] = acc;
}

// ---------- contraction + oc MLP, weights LDS-staged, 16 atoms/block ----------
template <bool ACC>
__global__ void k_dmlp(const float* __restrict__ co, const float* __restrict__ ccoef,
                       const float* __restrict__ cct_l,
                       const float* __restrict__ W1, const float* __restrict__ b1,
                       const float* __restrict__ g,  const float* __restrict__ be,
                       const float* __restrict__ W2t, const float* __restrict__ b2,
                       const float* __restrict__ S_in, float* __restrict__ S_out) {
    __shared__ float w1_s[4096];   // raw [i][o] layout: column reads are conflict-free
    __shared__ float cct_s[1024];
    __shared__ float w2_s[512];    // [o][i]
    __shared__ float b1_s[64], g_s[64], be_s[64], b2_s[8];
    __shared__ float dens_s[4][64], h_s[4][64];
    int t = threadIdx.x;
    for (int i = t; i < 1024; i += 256) ((float4*)w1_s)[i] = ((const float4*)W1)[i];
    if (t < 256) ((float4*)cct_s)[t] = ((const float4*)cct_l)[t];
    if (t < 128) ((float4*)w2_s)[t] = ((const float4*)W2t)[t];
    if (t < 64) { b1_s[t] = b1[t]; g_s[t] = g[t]; be_s[t] = be[t]; }
    if (t >= 64 && t < 72) b2_s[t - 64] = b2[t - 64];
    __syncthreads();

    int lane = t & 63, slot = t >> 6;
    int abase = blockIdx.x * 16;
#pragma unroll 1
    for (int gi = 0; gi < 4; gi++) {
        int atom = abase + gi * 4 + slot;
        // unpack co (global broadcast, L2-hot)
        float cr[32];
        const float4* cp = (const float4*)(co + (size_t)atom * 32);
#pragma unroll
        for (int q = 0; q < 8; q++) {
            float4 v = cp[q];
            cr[q * 4 + 0] = v.x; cr[q * 4 + 1] = v.y; cr[q * 4 + 2] = v.z; cr[q * 4 + 3] = v.w;
        }
        const float4* c0 = (const float4*)(cct_s + lane * 8);
        const float4* c1 = (const float4*)(cct_s + 512 + lane * 8);
        float4 ca0 = c0[0], ca1 = c0[1];
        float4 cb0 = c1[0], cb1 = c1[1];
        float dens = ccoef[(size_t)atom * 64 + lane];
        {
            float s = cr[0] * ca0.x + cr[1] * ca0.y + cr[2] * ca0.z + cr[3] * ca0.w
                    + cr[4] * ca1.x + cr[5] * ca1.y + cr[6] * ca1.z + cr[7] * ca1.w;
            dens += s * s;
        }
#pragma unroll
        for (int jj = 1; jj < 4; jj++) {
            const float* cj = cr + jj * 8;
            float s = cj[0] * cb0.x + cj[1] * cb0.y + cj[2] * cb0.z + cj[3] * cb0.w
                    + cj[4] * cb1.x + cj[5] * cb1.y + cj[6] * cb1.z + cj[7] * cb1.w;
            dens += s * s;
        }
        dens_s[slot][lane] = dens;
        __syncthreads();

        float h = b1_s[lane];
#pragma unroll 16
        for (int i = 0; i < 64; i++) h += dens_s[slot][i] * w1_s[i * 64 + lane];
        h = ln_silu(h, g_s[lane], be_s[lane]);
        h_s[slot][lane] = h;
        __syncthreads();

        int o = lane >> 3, seg = lane & 7;
        const float4* w2p = (const float4*)(w2_s + o * 64 + seg * 8);
        const float4* hp  = (const float4*)(&h_s[slot][seg * 8]);
        float part = dot4(w2p[0], hp[0]) + dot4(w2p[1], hp[1]);
        part += __shfl_xor(part, 1, 64);
        part += __shfl_xor(part, 2, 64);
        part += __shfl_xor(part, 4, 64);
        if (seg == 0) {
            float val = part + b2_s[o];
            if (ACC) val += S_in[(size_t)atom * 8 + o];
            S_out[(size_t)atom * 8 + o] = val;
        }
        __syncthreads();
    }
}

// ---------- contraction + out MLP -> scalar, 16 atoms/block ----------
__global__ void k_dmlp_out(const float* __restrict__ co, const float* __restrict__ ccoef,
                           const float* __restrict__ cct_l, const int* __restrict__ spec,
                           const float* __restrict__ W1, const float* __restrict__ b1,
                           const float* __restrict__ g,  const float* __restrict__ be,
                           const float* __restrict__ W2, const float* __restrict__ b2,
                           float* __restrict__ out) {
    __shared__ float w1_s[4096];
    __shared__ float cct_s[1024];
    __shared__ float w2_s[64];
    __shared__ float b1_s[64], g_s[64], be_s[64];
    __shared__ float dens_s[4][64];
    int t = threadIdx.x;
    for (int i = t; i < 1024; i += 256) ((float4*)w1_s)[i] = ((const float4*)W1)[i];
    if (t < 256) ((float4*)cct_s)[t] = ((const float4*)cct_l)[t];
    if (t < 64) { b1_s[t] = b1[t]; g_s[t] = g[t]; be_s[t] = be[t]; w2_s[t] = W2[t]; }
    __syncthreads();

    int lane = t & 63, slot = t >> 6;
    int abase = blockIdx.x * 16;
    float b2v = b2[0];
#pragma unroll 1
    for (int gi = 0; gi < 4; gi++) {
        int atom = abase + gi * 4 + slot;
        float cr[32];
        const float4* cp = (const float4*)(co + (size_t)atom * 32);
#pragma unroll
        for (int q = 0; q < 8; q++) {
            float4 v = cp[q];
            cr[q * 4 + 0] = v.x; cr[q * 4 + 1] = v.y; cr[q * 4 + 2] = v.z; cr[q * 4 + 3] = v.w;
        }
        const float4* c0 = (const float4*)(cct_s + lane * 8);
        const float4* c1 = (const float4*)(cct_s + 512 + lane * 8);
        float4 ca0 = c0[0], ca1 = c0[1];
        float4 cb0 = c1[0], cb1 = c1[1];
        float dens = ccoef[(size_t)atom * 64 + lane];
        {
            float s = cr[0] * ca0.x + cr[1] * ca0.y + cr[2] * ca0.z + cr[3] * ca0.w
                    + cr[4] * ca1.x + cr[5] * ca1.y + cr[6] * ca1.z + cr[7] * ca1.w;
            dens += s * s;
        }
#pragma unroll
        for (int jj = 1; jj < 4; jj++) {
            const float* cj = cr + jj * 8;
            float s = cj[0] * cb0.x + cj[1] * cb0.y + cj[2] * cb0.z + cj[3] * cb0.w
                    + cj[4] * cb1.x + cj[5] * cb1.y + cj[6] * cb1.z + cj[7] * cb1.w;
            dens += s * s;
        }
        dens_s[slot][lane] = dens;
        __syncthreads();

        float h = b1_s[lane];
#pragma unroll 16
        for (int i = 0; i < 64; i++) h += dens_s[slot][i] * w1_s[i * 64 + lane];
        h = ln_silu(h, g_s[lane], be_s[lane]);
        float s = wred_sum(h * w2_s[lane]);
        if (lane == 0) {
            float mask = (spec[atom] >= 0) ? 1.f : 0.f;
            out[atom] = (s + b2v) * mask;
        }
        __syncthreads();
    }
}

extern "C" void kernel_launch(void* const* d_in, const int* in_sizes, int n_in,
                              void* d_out, int out_size, void* d_ws, size_t ws_size,
                              hipStream_t stream) {
    const float* cart   = (const float*)d_in[0];
    const int*   aidx   = (const int*)d_in[1];
    const int*   spec   = (const int*)d_in[2];
    const float* ccoeff = (const float*)d_in[4];
    const float* embn_W1 = (const float*)d_in[5];
    const float* embn_b1 = (const float*)d_in[6];
    const float* embn_g  = (const float*)d_in[7];
    const float* embn_be = (const float*)d_in[8];
    const float* embn_W2 = (const float*)d_in[9];
    const float* embn_b2 = (const float*)d_in[10];
    const float* embc_W1 = (const float*)d_in[11];
    const float* embc_b1 = (const float*)d_in[12];
    const float* embc_g  = (const float*)d_in[13];
    const float* embc_be = (const float*)d_in[14];
    const float* embc_W2 = (const float*)d_in[15];
    const float* embc_b2 = (const float*)d_in[16];
    const float* oc_W1 = (const float*)d_in[17];
    const float* oc_b1 = (const float*)d_in[18];
    const float* oc_g  = (const float*)d_in[19];
    const float* oc_be = (const float*)d_in[20];
    const float* oc_W2 = (const float*)d_in[21];
    const float* oc_b2 = (const float*)d_in[22];
    const float* out_W1 = (const float*)d_in[23];
    const float* out_b1 = (const float*)d_in[24];
    const float* out_g  = (const float*)d_in[25];
    const float* out_be = (const float*)d_in[26];
    const float* out_W2 = (const float*)d_in[27];
    const float* out_b2 = (const float*)d_in[28];

    float* outp = (float*)d_out;

    char* ws = (char*)d_ws;
    size_t off = 0;
    auto carve = [&](size_t bytes) { size_t o = off; off = (off + bytes + 255) & ~(size_t)255; return o; };
    float* ang_t   = (float*)(ws + carve((size_t)4 * NPADC * 4));
    float* rad_t   = (float*)(ws + carve((size_t)8 * NPADC * 4));
    float* prod_t  = (float*)(ws + carve((size_t)8 * NPADC * 4));
    int*   neigh   = (int*)(ws + carve((size_t)NPADC * 4));
    int*   plist   = (int*)(ws + carve((size_t)NPADC * 4));
    float* ccenter = (float*)(ws + carve((size_t)NATOMS * 64 * 4));
    float* co0     = (float*)(ws + carve((size_t)NATOMS * 32 * 4));
    float* cocur   = (float*)(ws + carve((size_t)NATOMS * 32 * 4));
    float* Sa      = (float*)(ws + carve((size_t)NATOMS * 8 * 4));
    float* Sb      = (float*)(ws + carve((size_t)NATOMS * 8 * 4));
    float* table   = (float*)(ws + carve((size_t)TBLN * 24 * 4));
    float* embc_W2t= (float*)(ws + carve(4096 * 4));
    float* oc_W2t  = (float*)(ws + carve(1536 * 4));
    float* cct     = (float*)(ws + carve(4096 * 4));
    int*   cnt     = (int*)(ws + carve((size_t)NATOMS * 4));
    int*   offs    = (int*)(ws + carve((size_t)(NATOMS + 1) * 4));
    int*   cursor  = (int*)(ws + carve((size_t)NATOMS * 4));

    hipMemsetAsync(cnt, 0, (size_t)NATOMS * 4, stream);
    hipMemsetAsync(plist, 0xFF, (size_t)NPADC * 4, stream);

    k_hist<<<NPAIRS / 256, 256, 0, stream>>>(aidx, cnt);
    k_scan<<<1, 1024, 0, stream>>>(cnt, offs, cursor);
    k_scatter<<<NPAIRS / 256, 256, 0, stream>>>(aidx, cursor, plist);

    k_prep<<<(9728 + 255) / 256, 256, 0, stream>>>(embc_W2, oc_W2, ccoeff,
                                                   embc_W2t, oc_W2t, cct);
    k_center<<<NATOMS / 4, 256, 0, stream>>>(spec, embc_W1, embc_b1, embc_g, embc_be,
                                             embc_W2t, embc_b2, ccenter);
    k_table<<<(TBLN + 3) / 4, 256, 0, stream>>>(embn_W1, embn_b1, embn_g, embn_be,
                                                embn_W2, embn_b2, table);

    k_pair2<<<NPADC / 256, 256, 0, stream>>>(cart, aidx, spec, table, plist, offs + NATOMS,
                                             outp, ang_t, rad_t, prod_t, neigh);

    // pass 0
    k_co<false><<<NATOMS / 8, 256, 0, stream>>>(offs, ang_t, prod_t, neigh, nullptr,
                                                nullptr, co0);
    k_dmlp<false><<<NATOMS / 16, 256, 0, stream>>>(co0, ccenter, cct + 0 * 1024,
                                                   oc_W1 + 0 * 4096, oc_b1 + 0 * 64,
                                                   oc_g + 0 * 64, oc_be + 0 * 64,
                                                   oc_W2t + 0 * 512, oc_b2 + 0 * 8,
                                                   nullptr, Sa);
    // pass 1
    k_co<true><<<NATOMS / 8, 256, 0, stream>>>(offs, ang_t, rad_t, neigh, co0, Sa, cocur);
    k_dmlp<true><<<NATOMS / 16, 256, 0, stream>>>(cocur, ccenter, cct + 1 * 1024,
                                                  oc_W1 + 1 * 4096, oc_b1 + 1 * 64,
                                                  oc_g + 1 * 64, oc_be + 1 * 64,
                                                  oc_W2t + 1 * 512, oc_b2 + 1 * 8,
                                                  Sa, Sb);
    // pass 2
    k_co<true><<<NATOMS / 8, 256, 0, stream>>>(offs, ang_t, rad_t, neigh, co0, Sb, cocur);
    k_dmlp<true><<<NATOMS / 16, 256, 0, stream>>>(cocur, ccenter, cct + 2 * 1024,
                                                  oc_W1 + 2 * 4096, oc_b1 + 2 * 64,
                                                  oc_g + 2 * 64, oc_be + 2 * 64,
                                                  oc_W2t + 2 * 512, oc_b2 + 2 * 8,
                                                  Sb, Sa);
    // final
    k_co<true><<<NATOMS / 8, 256, 0, stream>>>(offs, ang_t, rad_t, neigh, co0, Sa, cocur);
    k_dmlp_out<<<NATOMS / 16, 256, 0, stream>>>(cocur, ccenter, cct + 3 * 1024, spec,
                                                out_W1, out_b1, out_g, out_be,
                                                out_W2, out_b2, outp + (size_t)NPAIRS * 3);
}